// Round 1
// baseline (155.862 us; speedup 1.0000x reference)
//
#include <hip/hip_runtime.h>
#include <math.h>

#define DET 512
#define NA  180
#define OUT 362   // floor(sqrt(512^2/2))
#define RAD 181   // OUT/2

// ---------------------------------------------------------------------------
// Kernel 1: ramp filter as exact spatial convolution.
// Reference does: filtered = Re(IFFT(FFT(pad(x,1024)) * filt))[:512], where
// filt = 2*Re(FFT(f)) with the skimage ramp f. Since f is circularly even,
// h = ifft(filt) = 2f is real: h[0]=0.5, h[m odd]=-2/(pi*min(m,1024-m))^2,
// h[m even!=0]=0. For d,s in [0,512) there is no wrap aliasing, so
//   filtered[d] = 0.5*x[d] + sum_{|d-s| odd} x[s] * (-2/(pi*|d-s|)^2)
// Output layout: ft[b][a][d]  (detector contiguous per angle).
// ---------------------------------------------------------------------------
__global__ __launch_bounds__(256) void ramp_filter_kernel(
        const float* __restrict__ x, float* __restrict__ ft) {
    const int a = blockIdx.x;   // angle
    const int b = blockIdx.y;   // batch
    const int tid = threadIdx.x;

    __shared__ float xs[DET];
    __shared__ float wt2[DET / 2];   // wt2[k] = -2/(pi*(2k+1))^2

    // x is (B, 1, DET, NA): x[b][0][d][a] at ((b*DET)+d)*NA + a
    for (int i = tid; i < DET; i += 256)
        xs[i] = x[(b * DET + i) * NA + a];

    const float c = (float)(-2.0 / (M_PI * M_PI));
    for (int k = tid; k < DET / 2; k += 256) {
        float m = (float)(2 * k + 1);
        wt2[k] = c / (m * m);
    }
    __syncthreads();

    const int d0 = tid;        // outputs d0 and d0+256 share the s-parity set
    const int d1 = tid + 256;
    float acc0 = 0.5f * xs[d0];
    float acc1 = 0.5f * xs[d1];

    int s = (d0 & 1) ^ 1;      // opposite parity of d0
    for (int i = 0; i < DET / 2; ++i, s += 2) {
        float xv = xs[s];
        int m0 = abs(d0 - s);  // odd
        int m1 = abs(d1 - s);  // odd
        acc0 = fmaf(xv, wt2[m0 >> 1], acc0);
        acc1 = fmaf(xv, wt2[m1 >> 1], acc1);
    }

    float* o = ft + (b * NA + a) * DET;
    o[d0] = acc0;
    o[d1] = acc1;
}

// ---------------------------------------------------------------------------
// Kernel 2: backprojection. Grid (12,12,B); 32x32 pixel tile per block;
// each thread owns 4 pixels at (+0,+0),(+0,+16),(+16,+0),(+16,+16) so the
// 3 extra detector positions are 1 FMA each. Detector line double-buffered
// in LDS (one barrier per angle); trig tables in LDS.
// ---------------------------------------------------------------------------
__device__ __forceinline__ float interp1(const float* __restrict__ L, float pos) {
    float pf = floorf(pos);
    float fr = pos - pf;
    int i0 = (int)pf;
    int i0c = min(max(i0, 0), DET - 1);
    int i1c = min(max(i0 + 1, 0), DET - 1);
    float g0 = L[i0c];
    float g1 = L[i1c];
    float v = fmaf(fr, g1 - g0, g0);
    return (pos >= 0.0f && pos <= (float)(DET - 1)) ? v : 0.0f;
}

__global__ __launch_bounds__(256) void backproject_kernel(
        const float* __restrict__ ft, float* __restrict__ out) {
    const int b  = blockIdx.z;
    const int r0 = blockIdx.y * 32;
    const int c0 = blockIdx.x * 32;
    const int tid = threadIdx.x;
    const int tx = tid & 15;
    const int ty = tid >> 4;

    __shared__ float line[2][DET];
    __shared__ float ct[NA], st[NA];

    if (tid < NA) {
        float th = (float)tid * (float)(M_PI / 180.0);
        sincosf(th, &st[tid], &ct[tid]);
    }

    const float* base = ft + b * NA * DET;
    line[0][tid]       = base[tid];
    line[0][tid + 256] = base[tid + 256];
    __syncthreads();

    const float xpr = (float)(r0 + ty - RAD);   // row coordinate
    const float ypr = (float)(c0 + tx - RAD);   // col coordinate

    float a00 = 0.0f, a01 = 0.0f, a10 = 0.0f, a11 = 0.0f;

    for (int a = 0; a < NA; ++a) {
        const int cur = a & 1;
        if (a + 1 < NA) {  // prefetch next angle into the other buffer
            const float* nb = base + (a + 1) * DET;
            line[cur ^ 1][tid]       = nb[tid];
            line[cur ^ 1][tid + 256] = nb[tid + 256];
        }
        const float cv = ct[a];
        const float sv = st[a];
        // pos = ypr*cos - xpr*sin + det/2
        float p00 = fmaf(ypr, cv, fmaf(-xpr, sv, 256.0f));
        float p01 = fmaf(16.0f, cv, p00);   // col+16
        float p10 = fmaf(-16.0f, sv, p00);  // row+16
        float p11 = fmaf(-16.0f, sv, p01);  // row+16, col+16

        const float* L = line[cur];
        a00 += interp1(L, p00);
        a01 += interp1(L, p01);
        a10 += interp1(L, p10);
        a11 += interp1(L, p11);
        __syncthreads();
    }

    const float scale = (float)(M_PI / (2.0 * NA));
    const int r = r0 + ty;
    const int c = c0 + tx;
    float* ob = out + b * OUT * OUT;
    if (r < OUT) {
        if (c < OUT)      ob[r * OUT + c]        = a00 * scale;
        if (c + 16 < OUT) ob[r * OUT + c + 16]   = a01 * scale;
    }
    if (r + 16 < OUT) {
        if (c < OUT)      ob[(r + 16) * OUT + c]      = a10 * scale;
        if (c + 16 < OUT) ob[(r + 16) * OUT + c + 16] = a11 * scale;
    }
}

extern "C" void kernel_launch(void* const* d_in, const int* in_sizes, int n_in,
                              void* d_out, int out_size, void* d_ws, size_t ws_size,
                              hipStream_t stream) {
    const float* x = (const float*)d_in[0];
    float* ft  = (float*)d_ws;     // needs B*NA*DET*4 = 1.47 MB scratch
    float* out = (float*)d_out;

    const int B = in_sizes[0] / (DET * NA);   // 4

    ramp_filter_kernel<<<dim3(NA, B), 256, 0, stream>>>(x, ft);
    backproject_kernel<<<dim3((OUT + 31) / 32, (OUT + 31) / 32, B), 256, 0, stream>>>(ft, out);
}

// Round 2
// 104.859 us; speedup vs baseline: 1.4864x; 1.4864x over previous
//
#include <hip/hip_runtime.h>
#include <math.h>

#define DET 512
#define NA  180
#define OUT 362   // floor(sqrt(512^2/2))
#define RAD 181   // OUT/2

#define NSPLIT 3        // angle partitions per (b, tile)
#define APB    60       // angles per block (NA / NSPLIT)
#define CHUNK  10       // angle lines staged per barrier
#define LSTRIDE 516     // line stride in floats (516*4 bytes, 16B-aligned lines)

// ---------------------------------------------------------------------------
// Compile-time tables (constant memory -> scalar loads, uniform indices).
// ---------------------------------------------------------------------------
constexpr double PI_D = 3.14159265358979323846;

constexpr double tsin(double x) {  // |x| <= pi/4
    double x2 = x * x;
    return x * (1.0 + x2 * (-1.0/6 + x2 * (1.0/120 + x2 * (-1.0/5040 +
               x2 * (1.0/362880 + x2 * (-1.0/39916800))))));
}
constexpr double tcos(double x) {  // |x| <= pi/4
    double x2 = x * x;
    return 1.0 + x2 * (-0.5 + x2 * (1.0/24 + x2 * (-1.0/720 +
               x2 * (1.0/40320 + x2 * (-1.0/3628800)))));
}

struct Trig { float c[NA]; float s[NA]; };
constexpr Trig make_trig() {
    Trig t{};
    constexpr double r = PI_D / 180.0;
    for (int k = 0; k < NA; ++k) {
        double c, s;
        if (k <= 45)       { c =  tcos(k * r);          s =  tsin(k * r); }
        else if (k <= 90)  { c =  tsin((90 - k) * r);   s =  tcos((90 - k) * r); }
        else if (k <= 135) { c = -tsin((k - 90) * r);   s =  tcos((k - 90) * r); }
        else               { c = -tcos((180 - k) * r);  s =  tsin((180 - k) * r); }
        t.c[k] = (float)c; t.s[k] = (float)s;
    }
    return t;
}
__device__ constexpr Trig TRIG = make_trig();

struct WTbl { float w[DET / 2]; };
constexpr WTbl make_wt() {   // w[k] = -2 / (pi * (2k+1))^2
    WTbl t{};
    for (int k = 0; k < DET / 2; ++k) {
        double m = (double)(2 * k + 1);
        t.w[k] = (float)(-2.0 / (PI_D * PI_D * m * m));
    }
    return t;
}
__device__ constexpr WTbl WTC = make_wt();

// ---------------------------------------------------------------------------
// Kernel 1: ramp filter as exact spatial convolution (symmetric-tap form):
//   filtered[d] = 0.5*x[d] + sum_{m odd} w_m * (x[d-m] + x[d+m]),  x zero-padded
// Output layout: ft[b][a][d] (detector contiguous per angle).
// ---------------------------------------------------------------------------
__global__ __launch_bounds__(512) void ramp_filter_kernel(
        const float* __restrict__ x, float* __restrict__ ft) {
    const int a = blockIdx.x;
    const int b = blockIdx.y;
    const int tid = threadIdx.x;   // 0..511

    __shared__ float xs[3 * DET];  // [0,512) zeros | [512,1024) data | [1024,1536) zeros

    xs[tid]        = 0.0f;
    xs[1024 + tid] = 0.0f;
    // x is (B, 1, DET, NA): column read (strided; L2-served, once per element)
    xs[512 + tid]  = x[(b * DET + tid) * NA + a];
    __syncthreads();

    const float* p = xs + 512 + tid;
    float acc = 0.5f * p[0];
    #pragma unroll 4
    for (int k = 0; k < DET / 2; ++k) {
        int m = 2 * k + 1;
        acc = fmaf(WTC.w[k], p[-m] + p[m], acc);
    }
    ft[(b * NA + a) * DET + tid] = acc;
}

// ---------------------------------------------------------------------------
// Kernel 2: backprojection. Grid (12,12,B*NSPLIT); 32x32 pixel tile;
// 4 pixels/thread; CHUNK angle-lines staged per barrier; trig from constant
// memory; no clamps in the lerp (valid pixels have pos in [0.03, 511.97]);
// partials combined with atomicAdd onto memset-zeroed output.
// ---------------------------------------------------------------------------
__device__ __forceinline__ float interp1(const float* __restrict__ L, float pos) {
    float pf = floorf(pos);
    int   i0 = (int)pf;
    float fr = pos - pf;
    float g0 = L[i0];
    float g1 = L[i0 + 1];          // L[512] is a zero sentinel
    float v  = fmaf(fr, g1 - g0, g0);
    return pos <= (float)(DET - 1) ? v : 0.0f;
}

__global__ __launch_bounds__(256) void backproject_kernel(
        const float* __restrict__ ft, float* __restrict__ out) {
    const int bz = blockIdx.z;
    const int b  = bz / NSPLIT;
    const int sp = bz - b * NSPLIT;
    const int r0 = blockIdx.y * 32;
    const int c0 = blockIdx.x * 32;
    const int tid = threadIdx.x;
    const int tx = tid & 15;
    const int ty = tid >> 4;

    __shared__ float line[CHUNK * LSTRIDE];

    // zero sentinels at [c][512] (never overwritten by staging)
    if (tid < CHUNK) line[tid * LSTRIDE + 512] = 0.0f;

    // clamp base coordinate for guard pixels (r/c >= OUT) so their pos stays
    // in-range; their stores are guarded off below.
    const float xpr = (float)(min(r0 + ty, OUT - 1) - RAD);   // row coord
    const float ypr = (float)(min(c0 + tx, OUT - 1) - RAD);   // col coord

    float a00 = 0.0f, a01 = 0.0f, a10 = 0.0f, a11 = 0.0f;

    const float* base = ft + (b * NA + sp * APB) * DET;

    for (int rd = 0; rd < APB / CHUNK; ++rd) {
        __syncthreads();
        const float4* g = (const float4*)(base + rd * CHUNK * DET);
        #pragma unroll
        for (int k = 0; k < (CHUNK * DET / 4) / 256; ++k) {
            int j4 = tid + k * 256;                 // float4 index in chunk
            float4 v = g[j4];
            int c = j4 >> 7;                        // line within chunk
            int d = (j4 & 127) << 2;                // detector offset
            *(float4*)&line[c * LSTRIDE + d] = v;
        }
        __syncthreads();

        const int abase = sp * APB + rd * CHUNK;
        #pragma unroll
        for (int i = 0; i < CHUNK; ++i) {
            const float cv = TRIG.c[abase + i];
            const float sv = TRIG.s[abase + i];
            // pos = ypr*cos - xpr*sin + det/2
            float p00 = fmaf(ypr, cv, fmaf(xpr, -sv, 256.0f));
            float p01 = fmaf(16.0f, cv, p00);       // col+16
            float p10 = fmaf(-16.0f, sv, p00);      // row+16
            float p11 = fmaf(-16.0f, sv, p01);      // row+16, col+16
            const float* L = line + i * LSTRIDE;
            a00 += interp1(L, p00);
            a01 += interp1(L, p01);
            a10 += interp1(L, p10);
            a11 += interp1(L, p11);
        }
    }

    const float scale = (float)(PI_D / (2.0 * NA));
    const int r = r0 + ty;
    const int c = c0 + tx;
    float* ob = out + b * OUT * OUT;
    if (r < OUT) {
        if (c < OUT)      atomicAdd(&ob[r * OUT + c],      a00 * scale);
        if (c + 16 < OUT) atomicAdd(&ob[r * OUT + c + 16], a01 * scale);
    }
    if (r + 16 < OUT) {
        if (c < OUT)      atomicAdd(&ob[(r + 16) * OUT + c],      a10 * scale);
        if (c + 16 < OUT) atomicAdd(&ob[(r + 16) * OUT + c + 16], a11 * scale);
    }
}

extern "C" void kernel_launch(void* const* d_in, const int* in_sizes, int n_in,
                              void* d_out, int out_size, void* d_ws, size_t ws_size,
                              hipStream_t stream) {
    const float* x = (const float*)d_in[0];
    float* ft  = (float*)d_ws;     // B*NA*DET*4 = 1.47 MB scratch
    float* out = (float*)d_out;

    const int B = in_sizes[0] / (DET * NA);   // 4

    hipMemsetAsync(out, 0, (size_t)out_size * sizeof(float), stream);
    ramp_filter_kernel<<<dim3(NA, B), 512, 0, stream>>>(x, ft);
    backproject_kernel<<<dim3((OUT + 31) / 32, (OUT + 31) / 32, B * NSPLIT),
                         256, 0, stream>>>(ft, out);
}